// Round 1
// baseline (268.965 us; speedup 1.0000x reference)
//
#include <hip/hip_runtime.h>

#define BB 1024
#define TT 512
#define KK 64

__device__ __forceinline__ float lane_bcast(float v, int lane) {
    return __uint_as_float(__builtin_amdgcn_readlane(__float_as_uint(v), lane));
}

__device__ __forceinline__ float wave_sum(float v) {
#pragma unroll
    for (int off = 1; off < 64; off <<= 1) v += __shfl_xor(v, off);
    return v;
}

__device__ __forceinline__ float wave_max(float v) {
#pragma unroll
    for (int off = 1; off < 64; off <<= 1) v = fmaxf(v, __shfl_xor(v, off));
    return v;
}

// One wave (64 lanes) per batch element. Lane j owns state j.
// alpha kept as (m, p[j] = exp(alpha[j]-m)) with sum_j p = 1 after each step.
__global__ __launch_bounds__(64, 2) void crf_fwd(
    const float* __restrict__ logits,
    const float* __restrict__ trans,
    const int* __restrict__ gold,
    const int* __restrict__ seq_len,
    float* __restrict__ ws,      // per-b contribution (if use_ws)
    float* __restrict__ out,     // atomic fallback
    int use_ws)
{
    const int b = blockIdx.x;
    const int j = threadIdx.x & 63;
    const float* lg = logits + (size_t)b * (TT * KK);
    const int* gd = gold + (size_t)b * TT;
    const int L = seq_len[b];

    // E[j][k] = exp(trans[j][k]) held in registers (row j per lane).
    float E[KK];
#pragma unroll
    for (int k = 0; k < KK; k += 4) {
        float4 v4 = *reinterpret_cast<const float4*>(trans + j * KK + k);
        E[k + 0] = __expf(v4.x);
        E[k + 1] = __expf(v4.y);
        E[k + 2] = __expf(v4.z);
        E[k + 3] = __expf(v4.w);
    }

    // ---- t = 0 init ----
    float a0 = lg[j];
    float mx = wave_max(a0);
    float e0 = __expf(a0 - mx);
    float c0 = wave_sum(e0);
    float p = e0 / c0;
    float m = mx + __logf(c0);

    int g_prev = gd[0];
    float acc_first = (j == g_prev) ? a0 : 0.0f;  // t=0 always valid (L >= 2)
    float acc_second = 0.0f;

    // ---- software pipeline init (t=1 always executes since L >= 2) ----
    int g_cur = gd[1];
    int g_next = gd[2];
    float tr_cur = trans[g_prev * KK + g_cur];   // pair (0,1)
    float ltA = lg[1 * KK + j];
    float ltB = lg[2 * KK + j];
    float ltC = lg[3 * KK + j];

    for (int t = 1; t < TT; ++t) {
        if (t >= L) break;   // uniform: alpha frozen from here on, no more accumulation

        // prefetch (clamped)
        int t3 = t + 3; t3 = (t3 > TT - 1) ? TT - 1 : t3;
        int t2 = t + 2; t2 = (t2 > TT - 1) ? TT - 1 : t2;
        float ltD = lg[t3 * KK + j];
        int g_far = gd[t2];
        float tr_nxt = trans[g_cur * KK + g_next];   // pair (t, t+1), used next iter

        // s[j] = sum_k E[j][k] * p[k]; p[k] broadcast via v_readlane
        float s0 = 0.f, s1 = 0.f, s2 = 0.f, s3 = 0.f;
#pragma unroll
        for (int k = 0; k < KK; k += 4) {
            s0 = fmaf(E[k + 0], lane_bcast(p, k + 0), s0);
            s1 = fmaf(E[k + 1], lane_bcast(p, k + 1), s1);
            s2 = fmaf(E[k + 2], lane_bcast(p, k + 2), s2);
            s3 = fmaf(E[k + 3], lane_bcast(p, k + 3), s3);
        }
        float s = (s0 + s1) + (s2 + s3);

        float q = s * __expf(ltA);          // exp(alpha_new[j] - m)
        float c = wave_sum(q);              // uniform across lanes (symmetric butterfly)
        p = q * (1.0f / c);                 // renormalize: sum p = 1
        m += __logf(c);

        acc_first  += (j == g_cur) ? ltA : 0.0f;
        acc_second += (j == 0) ? tr_cur : 0.0f;

        // rotate pipeline
        ltA = ltB; ltB = ltC; ltC = ltD;
        g_cur = g_next; g_next = g_far;
        tr_cur = tr_nxt;
    }

    float sump = wave_sum(p);               // ~1.0, include for accuracy
    float third_b = m + __logf(sump);
    float first_b = wave_sum(acc_first);

    if (j == 0) {
        float contrib = (third_b - first_b - acc_second) * (1.0f / (float)BB);
        if (use_ws) ws[b] = contrib;
        else atomicAdd(out, contrib);
    }
}

// Deterministic fixed-order reduction of the 1024 per-b contributions.
__global__ void crf_reduce(const float* __restrict__ ws, float* __restrict__ out) {
    int tid = threadIdx.x;  // 256 threads
    float v = ws[tid] + ws[tid + 256] + ws[tid + 512] + ws[tid + 768];
    v = wave_sum(v);
    __shared__ float sm[4];
    if ((tid & 63) == 0) sm[tid >> 6] = v;
    __syncthreads();
    if (tid == 0) out[0] = (sm[0] + sm[1]) + (sm[2] + sm[3]);
}

extern "C" void kernel_launch(void* const* d_in, const int* in_sizes, int n_in,
                              void* d_out, int out_size, void* d_ws, size_t ws_size,
                              hipStream_t stream) {
    const float* logits = (const float*)d_in[0];
    const float* trans  = (const float*)d_in[1];
    const int*   gold   = (const int*)d_in[2];
    const int*   slen   = (const int*)d_in[3];
    float* out = (float*)d_out;

    int use_ws = (ws_size >= BB * sizeof(float)) ? 1 : 0;
    float* ws = (float*)d_ws;

    if (!use_ws) {
        hipMemsetAsync(out, 0, sizeof(float), stream);
    }
    hipLaunchKernelGGL(crf_fwd, dim3(BB), dim3(64), 0, stream,
                       logits, trans, gold, slen, ws, out, use_ws);
    if (use_ws) {
        hipLaunchKernelGGL(crf_reduce, dim3(1), dim3(256), 0, stream, ws, out);
    }
}

// Round 5
// 177.930 us; speedup vs baseline: 1.5116x; 1.5116x over previous
//
#include <hip/hip_runtime.h>

#define BB 1024
#define TT 512
#define KK 64

__device__ __forceinline__ float lane_bcast(float v, int lane) {
    return __uint_as_float(__builtin_amdgcn_readlane(__float_as_uint(v), lane));
}

__device__ __forceinline__ float wave_sum(float v) {
#pragma unroll
    for (int off = 1; off < 64; off <<= 1) v += __shfl_xor(v, off);
    return v;
}

__device__ __forceinline__ float wave_max(float v) {
#pragma unroll
    for (int off = 1; off < 64; off <<= 1) v = fmaxf(v, __shfl_xor(v, off));
    return v;
}

// One wave (64 lanes) per batch element. Lane j owns state j.
// alpha kept as (m, p[j]) with alpha[j] = m + log(p[j]).
// Renormalization (wave_sum + log + scale) DEFERRED to every 8 steps:
// per-step growth of sum(p) is bounded by max_j exp(lt_j) * max col-sum(E)
// ~= e^8 worst case -> e^64 over 8 steps, within fp32 range (e^88.7).
__global__ __launch_bounds__(64, 2) void crf_fwd(
    const float* __restrict__ logits,
    const float* __restrict__ trans,
    const int* __restrict__ gold,
    const int* __restrict__ seq_len,
    float* __restrict__ ws)
{
    const int b = blockIdx.x;
    const int j = threadIdx.x & 63;
    const float* lg = logits + (size_t)b * (TT * KK);
    const int* gd = gold + (size_t)b * TT;
    const int L = seq_len[b];

    // E[j][k] = exp(trans[j][k]) held in registers (row j per lane).
    float E[KK];
#pragma unroll
    for (int k = 0; k < KK; k += 4) {
        float4 v4 = *reinterpret_cast<const float4*>(trans + j * KK + k);
        E[k + 0] = __expf(v4.x);
        E[k + 1] = __expf(v4.y);
        E[k + 2] = __expf(v4.z);
        E[k + 3] = __expf(v4.w);
    }

    // ---- t = 0 init ----
    float a0 = lg[j];
    float mx = wave_max(a0);
    float p = __expf(a0 - mx);     // unnormalized; sum absorbed at checkpoints
    float m = mx;

    int g_prev = gd[0];
    float acc_first = (j == g_prev) ? a0 : 0.0f;  // t=0 always valid (L >= 2)
    float acc_second = 0.0f;

    // ---- software pipeline init (t=1 always executes since L >= 2) ----
    int g_cur = gd[1];
    int g_next = gd[2];
    float tr_cur = trans[g_prev * KK + g_cur];   // pair (0,1)
    float ltA = lg[1 * KK + j];
    float ltB = lg[2 * KK + j];
    float ltC = lg[3 * KK + j];

    for (int t = 1; t < TT; ++t) {
        if (t >= L) break;   // uniform: alpha frozen from here on

        // prefetch (clamped)
        int t3 = t + 3; t3 = (t3 > TT - 1) ? TT - 1 : t3;
        int t2 = t + 2; t2 = (t2 > TT - 1) ? TT - 1 : t2;
        float ltD = lg[t3 * KK + j];
        int g_far = gd[t2];
        float tr_nxt = trans[g_cur * KK + g_next];   // pair (t, t+1), used next iter

        // s[j] = sum_k E[j][k] * p[k]; p[k] broadcast via v_readlane
        float s0 = 0.f, s1 = 0.f, s2 = 0.f, s3 = 0.f;
#pragma unroll
        for (int k = 0; k < KK; k += 4) {
            s0 = fmaf(E[k + 0], lane_bcast(p, k + 0), s0);
            s1 = fmaf(E[k + 1], lane_bcast(p, k + 1), s1);
            s2 = fmaf(E[k + 2], lane_bcast(p, k + 2), s2);
            s3 = fmaf(E[k + 3], lane_bcast(p, k + 3), s3);
        }
        float s = (s0 + s1) + (s2 + s3);

        p = s * __expf(ltA);                 // unnormalized exp(alpha_new[j] - m)

        // deferred renormalization: every 8 steps (uniform branch)
        if ((t & 7) == 0) {
            float c = wave_sum(p);
            p *= (1.0f / c);
            m += __logf(c);
        }

        acc_first  += (j == g_cur) ? ltA : 0.0f;
        acc_second += (j == 0) ? tr_cur : 0.0f;

        // rotate pipeline
        ltA = ltB; ltB = ltC; ltC = ltD;
        g_cur = g_next; g_next = g_far;
        tr_cur = tr_nxt;
    }

    float sump = wave_sum(p);
    float third_b = m + __logf(sump);
    float first_b = wave_sum(acc_first);

    if (j == 0) {
        ws[b] = (third_b - first_b - acc_second) * (1.0f / (float)BB);
    }
}

// Deterministic fixed-order reduction of the 1024 per-b contributions.
__global__ void crf_reduce(const float* __restrict__ ws, float* __restrict__ out) {
    int tid = threadIdx.x;  // 256 threads
    float v = ws[tid] + ws[tid + 256] + ws[tid + 512] + ws[tid + 768];
    v = wave_sum(v);
    __shared__ float sm[4];
    if ((tid & 63) == 0) sm[tid >> 6] = v;
    __syncthreads();
    if (tid == 0) out[0] = (sm[0] + sm[1]) + (sm[2] + sm[3]);
}

extern "C" void kernel_launch(void* const* d_in, const int* in_sizes, int n_in,
                              void* d_out, int out_size, void* d_ws, size_t ws_size,
                              hipStream_t stream) {
    const float* logits = (const float*)d_in[0];
    const float* trans  = (const float*)d_in[1];
    const int*   gold   = (const int*)d_in[2];
    const int*   slen   = (const int*)d_in[3];
    float* out = (float*)d_out;
    float* ws = (float*)d_ws;

    hipLaunchKernelGGL(crf_fwd, dim3(BB), dim3(64), 0, stream,
                       logits, trans, gold, slen, ws);
    hipLaunchKernelGGL(crf_reduce, dim3(1), dim3(256), 0, stream, ws, out);
}

// Round 6
// 140.821 us; speedup vs baseline: 1.9100x; 1.2635x over previous
//
#include <hip/hip_runtime.h>

#define BB 1024
#define TT 512
#define KK 64
#define CH 8   // scan steps per chunk

__device__ __forceinline__ float lane_bcast(float v, int lane) {
    return __uint_as_float(__builtin_amdgcn_readlane(__float_as_uint(v), lane));
}

__device__ __forceinline__ float wave_sum(float v) {
#pragma unroll
    for (int off = 1; off < 64; off <<= 1) v += __shfl_xor(v, off);
    return v;
}

__device__ __forceinline__ float wave_max(float v) {
#pragma unroll
    for (int off = 1; off < 64; off <<= 1) v = fmaxf(v, __shfl_xor(v, off));
    return v;
}

// One wave per batch element. Lane j owns state j.
// alpha kept as (m, p[j]) with alpha[j] = m + log(p[j]); renorm once per chunk.
// first/second terms computed lane-parallel OUTSIDE the sequential scan.
__global__ __launch_bounds__(64, 1) void crf_fwd(
    const float* __restrict__ logits,
    const float* __restrict__ trans,
    const int* __restrict__ gold,
    const int* __restrict__ seq_len,
    float* __restrict__ ws)
{
    const int b = blockIdx.x;
    const int j = threadIdx.x & 63;
    const float* lg = logits + (size_t)b * (TT * KK);
    const int* gd = gold + (size_t)b * TT;
    const int L = seq_len[b];

    // ---- Phase A: lane-parallel first & second terms (off the scan) ----
    // lane j handles t = j, j+64, ..., j+448  (covers t = 0..511 exactly once)
    float af = 0.0f, as = 0.0f;
#pragma unroll
    for (int c = 0; c < TT / 64; ++c) {
        int t = c * 64 + j;
        if (t < L) {
            int g0 = gd[t];
            af += lg[t * KK + g0];
            if (t + 1 < L) {
                int g1 = gd[t + 1];
                as += trans[g0 * KK + g1];
            }
        }
    }

    // ---- E[j][k] = exp(trans[j][k]), row j per lane ----
    float E[KK];
#pragma unroll
    for (int k = 0; k < KK; k += 4) {
        float4 v4 = *reinterpret_cast<const float4*>(trans + j * KK + k);
        E[k + 0] = __expf(v4.x);
        E[k + 1] = __expf(v4.y);
        E[k + 2] = __expf(v4.z);
        E[k + 3] = __expf(v4.w);
    }

    // ---- t = 0 init ----
    float a0 = lg[j];
    float mx = wave_max(a0);
    float p = __expf(a0 - mx);   // unnormalized; scale absorbed at checkpoints
    float m = mx;

    // ---- preload chunk 0 (t = 1..8, clamped) ----
    float nlt[CH];
#pragma unroll
    for (int i = 0; i < CH; ++i) {
        int t = 1 + i; t = (t > TT - 1) ? TT - 1 : t;
        nlt[i] = lg[t * KK + j];
    }

    // ---- sequential scan, chunks of CH steps, fully unrolled inner ----
    for (int t0 = 1; t0 < L; t0 += CH) {
        // current chunk's exp(logits) — off the critical p-chain
        float elt[CH];
#pragma unroll
        for (int i = 0; i < CH; ++i) elt[i] = __expf(nlt[i]);

        // prefetch next chunk (consumed one full chunk later)
#pragma unroll
        for (int i = 0; i < CH; ++i) {
            int t = t0 + CH + i; t = (t > TT - 1) ? TT - 1 : t;
            nlt[i] = lg[t * KK + j];
        }

        // CH recursion steps, predicated on t < L (uniform per wave)
#pragma unroll
        for (int i = 0; i < CH; ++i) {
            int t = t0 + i;
            float s0 = 0.f, s1 = 0.f, s2 = 0.f, s3 = 0.f;
#pragma unroll
            for (int k = 0; k < KK; k += 4) {
                s0 = fmaf(E[k + 0], lane_bcast(p, k + 0), s0);
                s1 = fmaf(E[k + 1], lane_bcast(p, k + 1), s1);
                s2 = fmaf(E[k + 2], lane_bcast(p, k + 2), s2);
                s3 = fmaf(E[k + 3], lane_bcast(p, k + 3), s3);
            }
            float s = (s0 + s1) + (s2 + s3);
            float pn = s * elt[i];
            bool ok = (t < L) && (t < TT);
            p = ok ? pn : p;
        }

        // checkpoint renorm (unconditional; preserves alpha = m + log p even
        // for frozen waves). Growth over 8 steps bounded << fp32 range.
        float c = wave_sum(p);
        p *= (1.0f / c);
        m += __logf(c);
    }

    float sump = wave_sum(p);           // ~1.0; include for exactness
    float third_b = m + __logf(sump);
    float first_b = wave_sum(af);
    float second_b = wave_sum(as);

    if (j == 0) {
        ws[b] = (third_b - first_b - second_b) * (1.0f / (float)BB);
    }
}

// Deterministic fixed-order reduction of the 1024 per-b contributions.
__global__ void crf_reduce(const float* __restrict__ ws, float* __restrict__ out) {
    int tid = threadIdx.x;  // 256 threads
    float v = ws[tid] + ws[tid + 256] + ws[tid + 512] + ws[tid + 768];
    v = wave_sum(v);
    __shared__ float sm[4];
    if ((tid & 63) == 0) sm[tid >> 6] = v;
    __syncthreads();
    if (tid == 0) out[0] = (sm[0] + sm[1]) + (sm[2] + sm[3]);
}

extern "C" void kernel_launch(void* const* d_in, const int* in_sizes, int n_in,
                              void* d_out, int out_size, void* d_ws, size_t ws_size,
                              hipStream_t stream) {
    const float* logits = (const float*)d_in[0];
    const float* trans  = (const float*)d_in[1];
    const int*   gold   = (const int*)d_in[2];
    const int*   slen   = (const int*)d_in[3];
    float* out = (float*)d_out;
    float* ws = (float*)d_ws;

    hipLaunchKernelGGL(crf_fwd, dim3(BB), dim3(64), 0, stream,
                       logits, trans, gold, slen, ws);
    hipLaunchKernelGGL(crf_reduce, dim3(1), dim3(256), 0, stream, ws, out);
}

// Round 7
// 126.412 us; speedup vs baseline: 2.1277x; 1.1140x over previous
//
#include <hip/hip_runtime.h>

#define BB 1024
#define TT 512
#define KK 64
#define CH 8   // scan steps per chunk

__device__ __forceinline__ float lane_bcast(float v, int lane) {
    return __uint_as_float(__builtin_amdgcn_readlane(__float_as_uint(v), lane));
}

__device__ __forceinline__ float wave_sum(float v) {
#pragma unroll
    for (int off = 1; off < 64; off <<= 1) v += __shfl_xor(v, off);
    return v;
}

__device__ __forceinline__ float wave_max(float v) {
#pragma unroll
    for (int off = 1; off < 64; off <<= 1) v = fmaxf(v, __shfl_xor(v, off));
    return v;
}

// One wave per batch element. Lane j owns state j.
// E[j][k] = exp(trans[j][k]) held in 16 NAMED float4 registers (SROA-proof;
// round-6 showed a float E[64] array lands in scratch: VGPR_Count=60).
// alpha = m + log(p[j]); renorm once per chunk by broadcasting p[0] (exact).
__global__ __launch_bounds__(64, 1) void crf_fwd(
    const float* __restrict__ logits,
    const float* __restrict__ trans,
    const int* __restrict__ gold,
    const int* __restrict__ seq_len,
    float* __restrict__ ws)
{
    const int b = blockIdx.x;
    const int j = threadIdx.x & 63;
    const float* lg = logits + (size_t)b * (TT * KK);
    const int* gd = gold + (size_t)b * TT;
    const int L = seq_len[b];

    // ---- Phase A: lane-parallel first & second terms (off the scan) ----
    float af = 0.0f, asec = 0.0f;
#pragma unroll
    for (int c = 0; c < TT / 64; ++c) {
        int t = c * 64 + j;
        if (t < L) {
            int g0 = gd[t];
            af += lg[t * KK + g0];
            if (t + 1 < L) {
                int g1 = gd[t + 1];
                asec += trans[g0 * KK + g1];
            }
        }
    }

    // ---- E rows in named registers ----
    const float4* Et = reinterpret_cast<const float4*>(trans) + (size_t)j * (KK / 4);
#define DECLE(q) float4 E##q = Et[q]; \
    E##q.x = __expf(E##q.x); E##q.y = __expf(E##q.y); \
    E##q.z = __expf(E##q.z); E##q.w = __expf(E##q.w);
    DECLE(0)  DECLE(1)  DECLE(2)  DECLE(3)
    DECLE(4)  DECLE(5)  DECLE(6)  DECLE(7)
    DECLE(8)  DECLE(9)  DECLE(10) DECLE(11)
    DECLE(12) DECLE(13) DECLE(14) DECLE(15)
#undef DECLE

    // ---- t = 0 init ----
    float a0 = lg[j];
    float mx = wave_max(a0);
    float p = __expf(a0 - mx);   // unnormalized; scale absorbed at checkpoints
    float m = mx;

    // ---- preload chunk 0 (t = 1..8; TT-1 clamp unnecessary: 8 <= TT-1) ----
    float4 nl0, nl1;
    nl0.x = lg[1 * KK + j]; nl0.y = lg[2 * KK + j];
    nl0.z = lg[3 * KK + j]; nl0.w = lg[4 * KK + j];
    nl1.x = lg[5 * KK + j]; nl1.y = lg[6 * KK + j];
    nl1.z = lg[7 * KK + j]; nl1.w = lg[8 * KK + j];

#define MACQ(q) \
    s0 = fmaf(E##q.x, lane_bcast(p, (q) * 4 + 0), s0); \
    s1 = fmaf(E##q.y, lane_bcast(p, (q) * 4 + 1), s1); \
    s2 = fmaf(E##q.z, lane_bcast(p, (q) * 4 + 2), s2); \
    s3 = fmaf(E##q.w, lane_bcast(p, (q) * 4 + 3), s3);

#define STEP(ii, EL) { \
    float s0 = 0.f, s1 = 0.f, s2 = 0.f, s3 = 0.f; \
    MACQ(0)  MACQ(1)  MACQ(2)  MACQ(3) \
    MACQ(4)  MACQ(5)  MACQ(6)  MACQ(7) \
    MACQ(8)  MACQ(9)  MACQ(10) MACQ(11) \
    MACQ(12) MACQ(13) MACQ(14) MACQ(15) \
    float s = (s0 + s1) + (s2 + s3); \
    float pn = s * (EL); \
    p = (t0 + (ii) < L) ? pn : p; }

    // ---- sequential scan, chunks of CH=8 fully-unrolled steps ----
    for (int t0 = 1; t0 < L; t0 += CH) {
        // exp of current chunk's logits (off the critical p-chain)
        float4 el0, el1;
        el0.x = __expf(nl0.x); el0.y = __expf(nl0.y);
        el0.z = __expf(nl0.z); el0.w = __expf(nl0.w);
        el1.x = __expf(nl1.x); el1.y = __expf(nl1.y);
        el1.z = __expf(nl1.z); el1.w = __expf(nl1.w);

        // prefetch next chunk (consumed one full chunk later)
        {
            int tn = t0 + CH;
            int c0 = tn + 0; c0 = (c0 > TT - 1) ? TT - 1 : c0;
            int c1 = tn + 1; c1 = (c1 > TT - 1) ? TT - 1 : c1;
            int c2 = tn + 2; c2 = (c2 > TT - 1) ? TT - 1 : c2;
            int c3 = tn + 3; c3 = (c3 > TT - 1) ? TT - 1 : c3;
            int c4 = tn + 4; c4 = (c4 > TT - 1) ? TT - 1 : c4;
            int c5 = tn + 5; c5 = (c5 > TT - 1) ? TT - 1 : c5;
            int c6 = tn + 6; c6 = (c6 > TT - 1) ? TT - 1 : c6;
            int c7 = tn + 7; c7 = (c7 > TT - 1) ? TT - 1 : c7;
            nl0.x = lg[c0 * KK + j]; nl0.y = lg[c1 * KK + j];
            nl0.z = lg[c2 * KK + j]; nl0.w = lg[c3 * KK + j];
            nl1.x = lg[c4 * KK + j]; nl1.y = lg[c5 * KK + j];
            nl1.z = lg[c6 * KK + j]; nl1.w = lg[c7 * KK + j];
        }

        STEP(0, el0.x) STEP(1, el0.y) STEP(2, el0.z) STEP(3, el0.w)
        STEP(4, el1.x) STEP(5, el1.y) STEP(6, el1.z) STEP(7, el1.w)

        // cheap checkpoint renorm: divide by p[0] (any positive reference;
        // scale absorbed exactly into m). p[0] >= e^{-spread} * max(p),
        // spread across states is O(10) after one dense transition.
        float c = lane_bcast(p, 0);
        p *= (1.0f / c);
        m += __logf(c);
    }
#undef STEP
#undef MACQ

    float sump = wave_sum(p);
    float third_b = m + __logf(sump);
    float first_b = wave_sum(af);
    float second_b = wave_sum(asec);

    if (j == 0) {
        ws[b] = (third_b - first_b - second_b) * (1.0f / (float)BB);
    }
}

// Deterministic fixed-order reduction of the 1024 per-b contributions.
__global__ void crf_reduce(const float* __restrict__ ws, float* __restrict__ out) {
    int tid = threadIdx.x;  // 256 threads
    float v = ws[tid] + ws[tid + 256] + ws[tid + 512] + ws[tid + 768];
    v = wave_sum(v);
    __shared__ float sm[4];
    if ((tid & 63) == 0) sm[tid >> 6] = v;
    __syncthreads();
    if (tid == 0) out[0] = (sm[0] + sm[1]) + (sm[2] + sm[3]);
}

extern "C" void kernel_launch(void* const* d_in, const int* in_sizes, int n_in,
                              void* d_out, int out_size, void* d_ws, size_t ws_size,
                              hipStream_t stream) {
    const float* logits = (const float*)d_in[0];
    const float* trans  = (const float*)d_in[1];
    const int*   gold   = (const int*)d_in[2];
    const int*   slen   = (const int*)d_in[3];
    float* out = (float*)d_out;
    float* ws = (float*)d_ws;

    hipLaunchKernelGGL(crf_fwd, dim3(BB), dim3(64), 0, stream,
                       logits, trans, gold, slen, ws);
    hipLaunchKernelGGL(crf_reduce, dim3(1), dim3(256), 0, stream, ws, out);
}